// Round 2
// baseline (110.263 us; speedup 1.0000x reference)
//
#include <hip/hip_runtime.h>

// Problem constants (B=8, K=8192 from setup_inputs).
#define KPTS 8192
#define BATCH 8
#define TPB 256

#define NT 16                    // n-slices per batch
#define N_SLICE (KPTS / NT)      // 512
#define MT 8                     // m-tiles per batch
#define M_TILE (KPTS / MT)       // 1024
#define ACC (M_TILE / TPB)       // 4 adv points per thread

#define TPB2 1024                // phaseB block size

// ---------------- fast path: plain-store partial mins, 2 dispatches --------

// ws layout: ws[((b*NT + nt) * KPTS) + m] = min over this block's n-slice of
// ||ori_n - adv_m||^2.  Plain stores -> no init dispatch, no atomics.
__global__ __launch_bounds__(TPB) void phaseA_store(const float* __restrict__ adv,
                                                    const float* __restrict__ ori,
                                                    float* __restrict__ ws,
                                                    float* __restrict__ out) {
    __shared__ float4 sO[N_SLICE];   // (x, y, z, ||o||^2)

    const int bid = blockIdx.x;              // grid = B * MT * NT = 1024
    const int b  = bid >> 7;                 // / (MT*NT)
    const int mt = (bid >> 4) & (MT - 1);
    const int nt = bid & (NT - 1);
    const int tid = threadIdx.x;

    // Zero the output scalar for phaseB's atomicAdd; visible at next dispatch.
    if (bid == 0 && tid == 0) out[0] = 0.0f;

    const float* op = ori + ((size_t)b * KPTS + (size_t)nt * N_SLICE) * 3;
    for (int p = tid; p < N_SLICE; p += TPB) {
        float x = op[3 * p + 0];
        float y = op[3 * p + 1];
        float z = op[3 * p + 2];
        sO[p] = make_float4(x, y, z, x * x + y * y + z * z);
    }

    float nax[ACC], nay[ACC], naz[ACC], aa[ACC], mn[ACC];
    const float* ap = adv + ((size_t)b * KPTS + (size_t)mt * M_TILE) * 3;
#pragma unroll
    for (int i = 0; i < ACC; ++i) {
        int m = tid + i * TPB;
        float x = ap[3 * m + 0];
        float y = ap[3 * m + 1];
        float z = ap[3 * m + 2];
        nax[i] = -2.0f * x;
        nay[i] = -2.0f * y;
        naz[i] = -2.0f * z;
        aa[i]  = x * x + y * y + z * z;
        mn[i]  = __builtin_huge_valf();
    }

    __syncthreads();

    // 4 VALU per pair (3 fma + 1 min); sO[n] is a broadcast ds_read_b128.
#pragma unroll 8
    for (int n = 0; n < N_SLICE; ++n) {
        float4 o = sO[n];
#pragma unroll
        for (int i = 0; i < ACC; ++i) {
            float t = fmaf(o.x, nax[i], o.w);
            t = fmaf(o.y, nay[i], t);
            t = fmaf(o.z, naz[i], t);
            mn[i] = fminf(mn[i], t);
        }
    }

    float* wsb = ws + ((size_t)(b * NT + nt)) * KPTS + (size_t)mt * M_TILE;
#pragma unroll
    for (int i = 0; i < ACC; ++i)
        wsb[tid + i * TPB] = aa[i] + mn[i];
}

// One block per batch: min over NT slices, max over m, weighted mean.
__global__ __launch_bounds__(TPB2) void phaseB_big(const float* __restrict__ ws,
                                                   const float* __restrict__ w,
                                                   float* __restrict__ out) {
    const int b = blockIdx.x;
    const int tid = threadIdx.x;

    float mx = -__builtin_huge_valf();
    for (int m = tid; m < KPTS; m += TPB2) {
        float mn = __builtin_huge_valf();
#pragma unroll
        for (int t = 0; t < NT; ++t)
            mn = fminf(mn, ws[((size_t)(b * NT + t)) * KPTS + m]);
        mx = fmaxf(mx, mn);
    }

#pragma unroll
    for (int off = 32; off; off >>= 1)
        mx = fmaxf(mx, __shfl_down(mx, off, 64));

    __shared__ float red[TPB2 / 64];
    if ((tid & 63) == 0) red[tid >> 6] = mx;
    __syncthreads();
    if (tid == 0) {
        float m2 = red[0];
#pragma unroll
        for (int i = 1; i < TPB2 / 64; ++i) m2 = fmaxf(m2, red[i]);
        atomicAdd(out, m2 * w[b] * (1.0f / BATCH));
    }
}

// ---------------- fallback path (ws too small): atomicMin, 3 dispatches ----

__global__ void init_ws(float* ws, float* out) {
    int i = blockIdx.x * blockDim.x + threadIdx.x;
    if (i < BATCH * KPTS) ws[i] = __builtin_huge_valf();
    if (i == 0) out[0] = 0.0f;
}

__global__ __launch_bounds__(TPB) void phaseA_atomic(const float* __restrict__ adv,
                                                     const float* __restrict__ ori,
                                                     unsigned int* __restrict__ ws) {
    __shared__ float4 sO[N_SLICE];
    const int bid = blockIdx.x;              // grid = B * MT * NT = 1024
    const int b  = bid >> 7;
    const int mt = (bid >> 4) & (MT - 1);
    const int nt = bid & (NT - 1);
    const int tid = threadIdx.x;

    const float* op = ori + ((size_t)b * KPTS + (size_t)nt * N_SLICE) * 3;
    for (int p = tid; p < N_SLICE; p += TPB) {
        float x = op[3 * p + 0];
        float y = op[3 * p + 1];
        float z = op[3 * p + 2];
        sO[p] = make_float4(x, y, z, x * x + y * y + z * z);
    }

    float nax[ACC], nay[ACC], naz[ACC], aa[ACC], mn[ACC];
    const float* ap = adv + ((size_t)b * KPTS + (size_t)mt * M_TILE) * 3;
#pragma unroll
    for (int i = 0; i < ACC; ++i) {
        int m = tid + i * TPB;
        float x = ap[3 * m + 0];
        float y = ap[3 * m + 1];
        float z = ap[3 * m + 2];
        nax[i] = -2.0f * x;
        nay[i] = -2.0f * y;
        naz[i] = -2.0f * z;
        aa[i]  = x * x + y * y + z * z;
        mn[i]  = __builtin_huge_valf();
    }
    __syncthreads();

#pragma unroll 8
    for (int n = 0; n < N_SLICE; ++n) {
        float4 o = sO[n];
#pragma unroll
        for (int i = 0; i < ACC; ++i) {
            float t = fmaf(o.x, nax[i], o.w);
            t = fmaf(o.y, nay[i], t);
            t = fmaf(o.z, naz[i], t);
            mn[i] = fminf(mn[i], t);
        }
    }

    unsigned int* wsb = ws + (size_t)b * KPTS + (size_t)mt * M_TILE;
#pragma unroll
    for (int i = 0; i < ACC; ++i) {
        float v = fmaxf(aa[i] + mn[i], 0.0f);   // nonneg floats order as uints
        atomicMin(wsb + tid + i * TPB, __float_as_uint(v));
    }
}

__global__ __launch_bounds__(TPB) void phaseB_small(const float* __restrict__ ws,
                                                    const float* __restrict__ w,
                                                    float* __restrict__ out) {
    const int b = blockIdx.x;
    const int tid = threadIdx.x;
    float mx = -1.0f;
    for (int m = tid; m < KPTS; m += TPB)
        mx = fmaxf(mx, ws[(size_t)b * KPTS + m]);
#pragma unroll
    for (int off = 32; off; off >>= 1)
        mx = fmaxf(mx, __shfl_down(mx, off, 64));
    __shared__ float red[TPB / 64];
    if ((tid & 63) == 0) red[tid >> 6] = mx;
    __syncthreads();
    if (tid == 0) {
        float m2 = red[0];
#pragma unroll
        for (int i = 1; i < TPB / 64; ++i) m2 = fmaxf(m2, red[i]);
        atomicAdd(out, m2 * w[b] * (1.0f / BATCH));
    }
}

extern "C" void kernel_launch(void* const* d_in, const int* in_sizes, int n_in,
                              void* d_out, int out_size, void* d_ws, size_t ws_size,
                              hipStream_t stream) {
    const float* adv = (const float*)d_in[0];   // [B, K, 3]
    const float* ori = (const float*)d_in[1];   // [B, K, 3]
    const float* w   = (const float*)d_in[2];   // [B]
    float* out = (float*)d_out;
    float* ws  = (float*)d_ws;

    const size_t need = (size_t)BATCH * NT * KPTS * sizeof(float);  // 4 MB
    if (ws_size >= need) {
        phaseA_store<<<BATCH * MT * NT, TPB, 0, stream>>>(adv, ori, ws, out);
        phaseB_big<<<BATCH, TPB2, 0, stream>>>(ws, w, out);
    } else {
        init_ws<<<(BATCH * KPTS + TPB - 1) / TPB, TPB, 0, stream>>>(ws, out);
        phaseA_atomic<<<BATCH * MT * NT, TPB, 0, stream>>>(adv, ori, (unsigned int*)ws);
        phaseB_small<<<BATCH, TPB, 0, stream>>>(ws, w, out);
    }
}

// Round 3
// 96.388 us; speedup vs baseline: 1.1439x; 1.1439x over previous
//
#include <hip/hip_runtime.h>

// Problem constants (B=8, K=8192 from setup_inputs).
#define KPTS 8192
#define BATCH 8
#define TPB 256

#define NT 32                    // n-slices per batch
#define N_SLICE (KPTS / NT)      // 256
#define MT 8                     // m-tiles per batch
#define M_TILE (KPTS / MT)       // 1024
#define ACC (M_TILE / TPB)       // 4 adv points per thread

#define TPB2 1024                // phaseB block size

// ws[b*K + m] (uint) = running min over n of ||ori_n - adv_m||^2, as
// nonneg-float bit pattern (uint order == float order for nonneg).
// Initialized to 0xFFFFFFFF by hipMemsetAsync(0xFF) — graph-safe, no kernel.
__global__ __launch_bounds__(TPB) void phaseA(const float* __restrict__ adv,
                                              const float* __restrict__ ori,
                                              unsigned int* __restrict__ ws,
                                              float* __restrict__ out) {
    __shared__ float4 sO[N_SLICE];   // (x, y, z, ||o||^2)

    const int bid = blockIdx.x;              // grid = B * MT * NT = 2048
    const int b  = bid >> 8;                 // / (MT*NT)
    const int mt = (bid >> 5) & (MT - 1);
    const int nt = bid & (NT - 1);
    const int tid = threadIdx.x;

    // Zero the output scalar for phaseB's atomicAdd (kernel-order visible).
    if (bid == 0 && tid == 0) out[0] = 0.0f;

    // Stage this block's ori n-slice into LDS with precomputed ||o||^2.
    const float* op = ori + ((size_t)b * KPTS + (size_t)nt * N_SLICE) * 3;
    if (tid < N_SLICE) {
        float x = op[3 * tid + 0];
        float y = op[3 * tid + 1];
        float z = op[3 * tid + 2];
        sO[tid] = make_float4(x, y, z, x * x + y * y + z * z);
    }

    // Per-thread adv points: fold -2 into coords; aa added after the min.
    float nax[ACC], nay[ACC], naz[ACC], aa[ACC], mn[ACC];
    const float* ap = adv + ((size_t)b * KPTS + (size_t)mt * M_TILE) * 3;
#pragma unroll
    for (int i = 0; i < ACC; ++i) {
        int m = tid + i * TPB;
        float x = ap[3 * m + 0];
        float y = ap[3 * m + 1];
        float z = ap[3 * m + 2];
        nax[i] = -2.0f * x;
        nay[i] = -2.0f * y;
        naz[i] = -2.0f * z;
        aa[i]  = x * x + y * y + z * z;
        mn[i]  = __builtin_huge_valf();
    }

    __syncthreads();

    // 4 VALU per pair (3 fma + 1 min); sO[n] is a broadcast ds_read_b128.
#pragma unroll 8
    for (int n = 0; n < N_SLICE; ++n) {
        float4 o = sO[n];
#pragma unroll
        for (int i = 0; i < ACC; ++i) {
            float t = fmaf(o.x, nax[i], o.w);
            t = fmaf(o.y, nay[i], t);
            t = fmaf(o.z, naz[i], t);
            mn[i] = fminf(mn[i], t);
        }
    }

    // Cross-slice combine: nonneg floats order like uints.
    unsigned int* wsb = ws + (size_t)b * KPTS + (size_t)mt * M_TILE;
#pragma unroll
    for (int i = 0; i < ACC; ++i) {
        float v = fmaxf(aa[i] + mn[i], 0.0f);
        atomicMin(wsb + tid + i * TPB, __float_as_uint(v));
    }
}

// One block per batch: max over m, weighted mean into out.
__global__ __launch_bounds__(TPB2) void phaseB(const float* __restrict__ ws,
                                               const float* __restrict__ w,
                                               float* __restrict__ out) {
    const int b = blockIdx.x;
    const int tid = threadIdx.x;

    float mx = -1.0f;
#pragma unroll
    for (int m = tid; m < KPTS; m += TPB2)
        mx = fmaxf(mx, ws[(size_t)b * KPTS + m]);

#pragma unroll
    for (int off = 32; off; off >>= 1)
        mx = fmaxf(mx, __shfl_down(mx, off, 64));

    __shared__ float red[TPB2 / 64];
    if ((tid & 63) == 0) red[tid >> 6] = mx;
    __syncthreads();
    if (tid == 0) {
        float m2 = red[0];
#pragma unroll
        for (int i = 1; i < TPB2 / 64; ++i) m2 = fmaxf(m2, red[i]);
        atomicAdd(out, m2 * w[b] * (1.0f / BATCH));
    }
}

extern "C" void kernel_launch(void* const* d_in, const int* in_sizes, int n_in,
                              void* d_out, int out_size, void* d_ws, size_t ws_size,
                              hipStream_t stream) {
    const float* adv = (const float*)d_in[0];   // [B, K, 3]
    const float* ori = (const float*)d_in[1];   // [B, K, 3]
    const float* w   = (const float*)d_in[2];   // [B]
    float* out = (float*)d_out;
    unsigned int* ws = (unsigned int*)d_ws;     // B*K uints = 256 KB

    // 0xFFFFFFFF == +inf-ish top element for uint-ordered nonneg-float min.
    hipMemsetAsync(ws, 0xFF, (size_t)BATCH * KPTS * sizeof(unsigned int), stream);
    phaseA<<<BATCH * MT * NT, TPB, 0, stream>>>(adv, ori, ws, out);
    phaseB<<<BATCH, TPB2, 0, stream>>>((const float*)ws, w, out);
}